// Round 4
// baseline (291.706 us; speedup 1.0000x reference)
//
#include <hip/hip_runtime.h>
#include <hip/hip_bf16.h>

#define NROWS 8192
#define DIM   512
#define KSEL  20
#define PANEL 1024
#define NSURV 512

typedef unsigned int u32;
typedef unsigned long long u64;
typedef short bf16x8 __attribute__((ext_vector_type(8)));
typedef float f32x4 __attribute__((ext_vector_type(4)));
typedef ushort us4 __attribute__((ext_vector_type(4)));

typedef const void __attribute__((address_space(1))) as1_void;
typedef void __attribute__((address_space(3))) as3_void;

__device__ __forceinline__ void async_ld16(const ushort* g, ushort* l) {
    __builtin_amdgcn_global_load_lds((as1_void*)g, (as3_void*)l, 16, 0, 0);
}

// round-to-nearest-even f32 -> bf16 bits
__device__ __forceinline__ ushort f2bf(float f) {
    u32 u = __float_as_uint(f);
    return (ushort)((u + 0x7FFFu + ((u >> 16) & 1u)) >> 16);
}

// monotone map for one u16 bf16 pattern: integer compare == float compare
__device__ __forceinline__ u32 mono16(u32 r) {
    return r ^ (0x8000u | ((r >> 15) * 0x7FFFu));
}

// ---------------- normalize: fp32 rows -> unit-norm bf16 rows ----------------
__global__ __launch_bounds__(256) void k_norm(const float* __restrict__ x,
                                              ushort* __restrict__ xn) {
    int lane = threadIdx.x & 63;
    int wv   = threadIdx.x >> 6;
    int row  = blockIdx.x * 4 + wv;
    const float4* xr = (const float4*)(x + (size_t)row * DIM);
    float4 a = xr[2 * lane];
    float4 b = xr[2 * lane + 1];
    float ss = a.x*a.x + a.y*a.y + a.z*a.z + a.w*a.w
             + b.x*b.x + b.y*b.y + b.z*b.z + b.w*b.w;
    #pragma unroll
    for (int off = 32; off; off >>= 1) ss += __shfl_xor(ss, off);
    float sc = 1.0f / fmaxf(sqrtf(ss), 1e-12f);
    float v[8] = {a.x*sc, a.y*sc, a.z*sc, a.w*sc, b.x*sc, b.y*sc, b.z*sc, b.w*sc};
    union { ushort u[8]; uint4 q; } o;
    #pragma unroll
    for (int i = 0; i < 8; ++i) o.u[i] = f2bf(v[i]);
    *(uint4*)(xn + (size_t)row * DIM + lane * 8) = o.q;
}

// ---------------- GEMM: C = Xn * Xn^T (bf16 out), diag = -3.0 ----------------
// 128x128 tile, 4 waves (2x2), each wave 4x4 subtiles of 16x16x32 bf16 MFMA.
// TRI=true: blockIdx.x enumerates 2080 lower-triangle blocks (bx<=by); each
// writes its tile AND its mirrored transpose -> full symmetric C at half FLOPs.
// Epilogue additionally emits per-(row, 64-col-segment) MAX as monotone-u16
// keys into M[NROWS][128]: row-maxima cover segments bx*2+wc (each wave's own
// 64-col half); mirror col-maxima cover the transposed tile's segments by*2+wr.
template<bool TRI>
__global__ __launch_bounds__(256) void k_gemm(const ushort* __restrict__ xn,
                                              ushort* __restrict__ C,
                                              ushort* __restrict__ M,
                                              int row0) {
    __shared__ ushort lA[128 * 64];
    __shared__ ushort lB[128 * 64];
    int tid  = threadIdx.x;
    int lane = tid & 63, wv = tid >> 6;
    int wr = wv >> 1, wc = wv & 1;
    int q = lane >> 4, m = lane & 15;
    int bx, by;
    if (TRI) {
        int t = blockIdx.x;
        by = (int)((sqrtf(8.0f * (float)t + 1.0f) - 1.0f) * 0.5f);
        while ((by + 1) * (by + 2) / 2 <= t) ++by;
        while (by * (by + 1) / 2 > t) --by;
        bx = t - by * (by + 1) / 2;          // bx <= by
    } else {
        bx = blockIdx.x; by = blockIdx.y;
    }
    int grow0 = row0 + by * 128;   // A rows (global)
    int gcol0 = bx * 128;          // B rows = C cols (global)
    f32x4 acc[4][4] = {};

    int lr = lane >> 3;   // row within 8-row group
    int lc = lane & 7;    // LDS chunk slot this lane fills
    for (int kc = 0; kc < 8; ++kc) {
        #pragma unroll
        for (int t = 0; t < 4; ++t) {
            int rb  = wv * 32 + t * 8;     // wave-uniform row base
            int r   = rb + lr;
            int fch = lc ^ (r & 7);        // XOR chunk swizzle (bank-conflict-free)
            async_ld16(xn + (size_t)(grow0 + r) * DIM + kc * 64 + fch * 8, &lA[rb * 64]);
            async_ld16(xn + (size_t)(gcol0 + r) * DIM + kc * 64 + fch * 8, &lB[rb * 64]);
        }
        __syncthreads();
        #pragma unroll
        for (int s = 0; s < 2; ++s) {
            bf16x8 af[4], bfr[4];
            #pragma unroll
            for (int i = 0; i < 4; ++i) {
                int ra = wr * 64 + i * 16 + m;
                af[i]  = *(const bf16x8*)&lA[ra * 64 + (((s * 4 + q) ^ (ra & 7)) * 8)];
                int rb2 = wc * 64 + i * 16 + m;
                bfr[i] = *(const bf16x8*)&lB[rb2 * 64 + (((s * 4 + q) ^ (rb2 & 7)) * 8)];
            }
            #pragma unroll
            for (int i = 0; i < 4; ++i)
                #pragma unroll
                for (int j = 0; j < 4; ++j)
                    acc[i][j] = __builtin_amdgcn_mfma_f32_16x16x32_bf16(af[i], bfr[j], acc[i][j], 0, 0, 0);
        }
        __syncthreads();
    }
    // epilogue: C/D layout col=lane&15, row=quad*4+reg (m89/m91-verified)
    u32 cmk[4] = {0, 0, 0, 0};                 // per-j col maxima (mono keys)
    #pragma unroll
    for (int i = 0; i < 4; ++i) {
        u32 rmk[4] = {0, 0, 0, 0};             // per-reg row maxima (mono keys)
        #pragma unroll
        for (int j = 0; j < 4; ++j) {
            int c  = gcol0 + wc * 64 + j * 16 + m;            // global col
            int rb = by * 128 + wr * 64 + i * 16 + q * 4;      // local C row base
            ushort sv[4];
            #pragma unroll
            for (int reg = 0; reg < 4; ++reg) {
                int rl  = rb + reg;
                int grw = row0 + rl;
                ushort b = f2bf(acc[i][j][reg]);
                sv[reg] = (grw == c) ? (ushort)0xC040 : b;     // diag = -3.0
                C[(size_t)rl * NROWS + c] = sv[reg];
                u32 kk = mono16((u32)sv[reg]);
                rmk[reg] = max(rmk[reg], kk);
                cmk[j]   = max(cmk[j], kk);
            }
            if (TRI && bx != by) {                             // mirrored tile
                us4 pk4 = { sv[0], sv[1], sv[2], sv[3] };      // 4 consecutive rows
                *(us4*)&C[(size_t)c * NROWS + rb] = pk4;       // 8B store
            }
        }
        // row maxima: reduce over the 16 lanes (m) of each quad
        #pragma unroll
        for (int reg = 0; reg < 4; ++reg) {
            u32 k = rmk[reg];
            k = max(k, (u32)__shfl_xor((int)k, 1));
            k = max(k, (u32)__shfl_xor((int)k, 2));
            k = max(k, (u32)__shfl_xor((int)k, 4));
            k = max(k, (u32)__shfl_xor((int)k, 8));
            if (m == 0) {
                int grw = row0 + by * 128 + wr * 64 + i * 16 + q * 4 + reg;
                M[(size_t)grw * 128 + bx * 2 + wc] = (ushort)k;
            }
        }
    }
    if (TRI && bx != by) {
        // col maxima (mirror rows): reduce over the 4 quads (q)
        #pragma unroll
        for (int j = 0; j < 4; ++j) {
            u32 k = cmk[j];
            k = max(k, (u32)__shfl_xor((int)k, 16));
            k = max(k, (u32)__shfl_xor((int)k, 32));
            if (q == 0) {
                int gc = gcol0 + wc * 64 + j * 16 + m;
                M[(size_t)gc * 128 + by * 2 + wr] = (ushort)k;
            }
        }
    }
}

// ---------------- select: threshold from segment maxima, sparse scan --------
__device__ __forceinline__ void scan_mask(u64 mask, int par,
                                          const ushort* __restrict__ rowC,
                                          u32 T, volatile u32* s_surv,
                                          u32* s_cnt, int lane) {
    while (mask) {
        int b0 = __builtin_ctzll(mask); mask &= mask - 1;
        int b1 = b0, b2 = b0, b3 = b0;
        if (mask) { b1 = __builtin_ctzll(mask); mask &= mask - 1; }
        if (mask) { b2 = __builtin_ctzll(mask); mask &= mask - 1; }
        if (mask) { b3 = __builtin_ctzll(mask); mask &= mask - 1; }
        int s0 = 2 * b0 + par, s1 = 2 * b1 + par, s2 = 2 * b2 + par, s3 = 2 * b3 + par;
        ushort v0 = rowC[s0 * 64 + lane];
        ushort v1 = rowC[s1 * 64 + lane];
        ushort v2 = rowC[s2 * 64 + lane];
        ushort v3 = rowC[s3 * 64 + lane];
        u32 kk = mono16((u32)v0);
        if (kk >= T) { u32 p = atomicAdd(s_cnt, 1u); if (p < NSURV) s_surv[p] = (kk << 16) | (u32)(s0 * 64 + lane); }
        if (s1 != s0) { kk = mono16((u32)v1); if (kk >= T) { u32 p = atomicAdd(s_cnt, 1u); if (p < NSURV) s_surv[p] = (kk << 16) | (u32)(s1 * 64 + lane); } }
        if (s2 != s1) { kk = mono16((u32)v2); if (kk >= T) { u32 p = atomicAdd(s_cnt, 1u); if (p < NSURV) s_surv[p] = (kk << 16) | (u32)(s2 * 64 + lane); } }
        if (s3 != s2) { kk = mono16((u32)v3); if (kk >= T) { u32 p = atomicAdd(s_cnt, 1u); if (p < NSURV) s_surv[p] = (kk << 16) | (u32)(s3 * 64 + lane); } }
    }
}

__global__ __launch_bounds__(256) void k_select(const ushort* __restrict__ C,
                                                const ushort* __restrict__ M,
                                                const int* __restrict__ labels,
                                                int row0, float* __restrict__ acc) {
    __shared__ u32 s_surv[4][NSURV];
    __shared__ u32 s_cnt[4];
    int lane = threadIdx.x & 63;
    int wv   = threadIdx.x >> 6;
    int prow = blockIdx.x * 4 + wv;
    int grow = row0 + prow;
    const ushort* rowC = C + (size_t)prow * NROWS;

    if (lane == 0) s_cnt[wv] = 0;
    __syncthreads();

    // segment maxima (mono keys): lane holds segs 2*lane, 2*lane+1
    u32 pm  = *(const u32*)&M[(size_t)grow * 128 + 2 * lane];
    u32 klo = pm & 0xFFFFu, khi = pm >> 16;

    // T = 20th-largest DISTINCT segment max (valid lower bound on true 20th elem)
    u32 g0 = klo, g1 = khi, T = 1;
    for (int r = 0; r < KSEL; ++r) {
        u32 w = max(g0, g1);
        #pragma unroll
        for (int off = 32; off; off >>= 1) w = max(w, (u32)__shfl_xor((int)w, off));
        T = w;
        g0 = (g0 == w) ? 0u : g0;
        g1 = (g1 == w) ? 0u : g1;
    }
    if (T == 0) T = 1;

    // scan only segments whose max >= T (~22-26 of 128)
    u64 b0 = __ballot(klo >= T);
    u64 b1 = __ballot(khi >= T);
    scan_mask(b0, 0, rowC, T, s_surv[wv], &s_cnt[wv], lane);
    scan_mask(b1, 1, rowC, T, s_surv[wv], &s_cnt[wv], lane);
    __syncthreads();

    u32 cnt = min(s_cnt[wv], (u32)NSURV);
    u32 g[8];
    #pragma unroll
    for (int j = 0; j < 8; ++j) {
        u32 idx = (u32)lane + (u32)j * 64u;
        g[j] = (idx < cnt) ? s_surv[wv][idx] : 0u;
    }

    int mylab = labels[grow];
    float loss = 0.0f;
    for (int r = 0; r < KSEL; ++r) {
        u32 w = 0;
        #pragma unroll
        for (int j = 0; j < 8; ++j) w = max(w, g[j]);
        #pragma unroll
        for (int off = 32; off; off >>= 1) w = max(w, (u32)__shfl_xor((int)w, off));
        #pragma unroll
        for (int j = 0; j < 8; ++j) g[j] = (g[j] == w) ? 0u : g[j];  // col makes keys unique
        if (lane == 0) {
            u32 mono = w >> 16, col = w & 0xFFFFu;
            u32 raw  = (mono & 0x8000u) ? (mono ^ 0x8000u) : (mono ^ 0xFFFFu);
            float v  = __uint_as_float(raw << 16);
            float p  = (v + 1.0f) * 0.5f;
            bool t   = (labels[col] == mylab);
            float term = t ? fmaxf(logf(p), -100.0f) : fmaxf(log1pf(-p), -100.0f);
            loss -= term;
        }
    }
    if (lane == 0) atomicAdd(acc, loss);
}

__global__ void k_final(const float* __restrict__ acc, float* __restrict__ out) {
    out[0] = acc[0] * (1.0f / (float)(NROWS * KSEL));
}

extern "C" void kernel_launch(void* const* d_in, const int* in_sizes, int n_in,
                              void* d_out, int out_size, void* d_ws, size_t ws_size,
                              hipStream_t stream) {
    const float* batch  = (const float*)d_in[0];
    const int*   labels = (const int*)d_in[1];

    float*  accp = (float*)d_ws;
    ushort* xn   = (ushort*)((char*)d_ws + 256);
    ushort* C    = xn + (size_t)NROWS * DIM;
    // M (2 MB) lives in the batch input buffer (16 MB) — batch is only read by
    // k_norm, which completes (stream order) before k_gemm writes M.
    ushort* M    = (ushort*)d_in[0];

    size_t need_full = 256 + (size_t)NROWS * DIM * 2 + (size_t)NROWS * NROWS * 2;

    hipMemsetAsync(accp, 0, sizeof(float), stream);
    k_norm<<<NROWS / 4, 256, 0, stream>>>(batch, xn);

    if (ws_size >= need_full) {
        // full symmetric path: 2080 lower-triangle blocks, one select pass
        k_gemm<true><<<dim3(64 * 65 / 2), 256, 0, stream>>>(xn, C, M, 0);
        k_select<<<NROWS / 4, 256, 0, stream>>>(C, M, labels, 0, accp);
    } else {
        // fallback: panel path (24 MB of ws)
        for (int p = 0; p < NROWS / PANEL; ++p) {
            k_gemm<false><<<dim3(64, PANEL / 128), 256, 0, stream>>>(xn, C, M, p * PANEL);
            k_select<<<PANEL / 4, 256, 0, stream>>>(C, M, labels, p * PANEL, accp);
        }
    }
    k_final<<<1, 1, 0, stream>>>(accp, (float*)d_out);
}

// Round 5
// 179.242 us; speedup vs baseline: 1.6274x; 1.6274x over previous
//
#include <hip/hip_runtime.h>
#include <hip/hip_bf16.h>

#define NROWS 8192
#define DIM   512
#define KSEL  20
#define PANEL 1024
#define NSURV 512

typedef unsigned int u32;
typedef unsigned long long u64;
typedef short bf16x8 __attribute__((ext_vector_type(8)));
typedef float f32x4 __attribute__((ext_vector_type(4)));
typedef ushort us4 __attribute__((ext_vector_type(4)));

typedef const void __attribute__((address_space(1))) as1_void;
typedef void __attribute__((address_space(3))) as3_void;

__device__ __forceinline__ void async_ld16(const ushort* g, ushort* l) {
    __builtin_amdgcn_global_load_lds((as1_void*)g, (as3_void*)l, 16, 0, 0);
}

// round-to-nearest-even f32 -> bf16 bits
__device__ __forceinline__ ushort f2bf(float f) {
    u32 u = __float_as_uint(f);
    return (ushort)((u + 0x7FFFu + ((u >> 16) & 1u)) >> 16);
}

// monotone map for one u16 bf16 pattern: integer compare == float compare
__device__ __forceinline__ u32 mono16(u32 r) {
    return r ^ (0x8000u | ((r >> 15) * 0x7FFFu));
}

// ---------------- normalize: fp32 rows -> unit-norm bf16 rows ----------------
__global__ __launch_bounds__(256) void k_norm(const float* __restrict__ x,
                                              ushort* __restrict__ xn) {
    int lane = threadIdx.x & 63;
    int wv   = threadIdx.x >> 6;
    int row  = blockIdx.x * 4 + wv;
    const float4* xr = (const float4*)(x + (size_t)row * DIM);
    float4 a = xr[2 * lane];
    float4 b = xr[2 * lane + 1];
    float ss = a.x*a.x + a.y*a.y + a.z*a.z + a.w*a.w
             + b.x*b.x + b.y*b.y + b.z*b.z + b.w*b.w;
    #pragma unroll
    for (int off = 32; off; off >>= 1) ss += __shfl_xor(ss, off);
    float sc = 1.0f / fmaxf(sqrtf(ss), 1e-12f);
    float v[8] = {a.x*sc, a.y*sc, a.z*sc, a.w*sc, b.x*sc, b.y*sc, b.z*sc, b.w*sc};
    union { ushort u[8]; uint4 q; } o;
    #pragma unroll
    for (int i = 0; i < 8; ++i) o.u[i] = f2bf(v[i]);
    *(uint4*)(xn + (size_t)row * DIM + lane * 8) = o.q;
}

// ---------------- GEMM: C = Xn * Xn^T (bf16 out), diag = -3.0 ----------------
// 128x128 tile, 4 waves (2x2), each wave 4x4 subtiles of 16x16x32 bf16 MFMA.
// TRI=true: blockIdx.x enumerates 2080 lower-triangle blocks (bx<=by); each
// writes its tile AND its mirrored transpose -> full symmetric C at half FLOPs.
// Epilogue also emits per-(row, 64-col-segment) MAX as monotone-u16 keys into
// M[NROWS][128] (row maxima: seg bx*2+wc; mirror col maxima: seg by*2+wr).
template<bool TRI>
__global__ __launch_bounds__(256) void k_gemm(const ushort* __restrict__ xn,
                                              ushort* __restrict__ C,
                                              ushort* __restrict__ M,
                                              int row0) {
    __shared__ ushort lA[128 * 64];
    __shared__ ushort lB[128 * 64];
    int tid  = threadIdx.x;
    int lane = tid & 63, wv = tid >> 6;
    int wr = wv >> 1, wc = wv & 1;
    int q = lane >> 4, m = lane & 15;
    int bx, by;
    if (TRI) {
        int t = blockIdx.x;
        by = (int)((sqrtf(8.0f * (float)t + 1.0f) - 1.0f) * 0.5f);
        while ((by + 1) * (by + 2) / 2 <= t) ++by;
        while (by * (by + 1) / 2 > t) --by;
        bx = t - by * (by + 1) / 2;          // bx <= by
    } else {
        bx = blockIdx.x; by = blockIdx.y;
    }
    int grow0 = row0 + by * 128;   // A rows (global)
    int gcol0 = bx * 128;          // B rows = C cols (global)
    f32x4 acc[4][4] = {};

    int lr = lane >> 3;   // row within 8-row group
    int lc = lane & 7;    // LDS chunk slot this lane fills
    for (int kc = 0; kc < 8; ++kc) {
        #pragma unroll
        for (int t = 0; t < 4; ++t) {
            int rb  = wv * 32 + t * 8;     // wave-uniform row base
            int r   = rb + lr;
            int fch = lc ^ (r & 7);        // XOR chunk swizzle (bank-conflict-free)
            async_ld16(xn + (size_t)(grow0 + r) * DIM + kc * 64 + fch * 8, &lA[rb * 64]);
            async_ld16(xn + (size_t)(gcol0 + r) * DIM + kc * 64 + fch * 8, &lB[rb * 64]);
        }
        __syncthreads();
        #pragma unroll
        for (int s = 0; s < 2; ++s) {
            bf16x8 af[4], bfr[4];
            #pragma unroll
            for (int i = 0; i < 4; ++i) {
                int ra = wr * 64 + i * 16 + m;
                af[i]  = *(const bf16x8*)&lA[ra * 64 + (((s * 4 + q) ^ (ra & 7)) * 8)];
                int rb2 = wc * 64 + i * 16 + m;
                bfr[i] = *(const bf16x8*)&lB[rb2 * 64 + (((s * 4 + q) ^ (rb2 & 7)) * 8)];
            }
            #pragma unroll
            for (int i = 0; i < 4; ++i)
                #pragma unroll
                for (int j = 0; j < 4; ++j)
                    acc[i][j] = __builtin_amdgcn_mfma_f32_16x16x32_bf16(af[i], bfr[j], acc[i][j], 0, 0, 0);
        }
        __syncthreads();
    }
    // epilogue: C/D layout col=lane&15, row=quad*4+reg (m89/m91-verified)
    u32 cmk[4] = {0, 0, 0, 0};                 // per-j col maxima (mono keys)
    #pragma unroll
    for (int i = 0; i < 4; ++i) {
        u32 rmk[4] = {0, 0, 0, 0};             // per-reg row maxima (mono keys)
        #pragma unroll
        for (int j = 0; j < 4; ++j) {
            int c  = gcol0 + wc * 64 + j * 16 + m;            // global col
            int rb = by * 128 + wr * 64 + i * 16 + q * 4;      // local C row base
            ushort sv[4];
            #pragma unroll
            for (int reg = 0; reg < 4; ++reg) {
                int rl  = rb + reg;
                int grw = row0 + rl;
                ushort b = f2bf(acc[i][j][reg]);
                sv[reg] = (grw == c) ? (ushort)0xC040 : b;     // diag = -3.0
                C[(size_t)rl * NROWS + c] = sv[reg];
                u32 kk = mono16((u32)sv[reg]);
                rmk[reg] = max(rmk[reg], kk);
                cmk[j]   = max(cmk[j], kk);
            }
            if (TRI && bx != by) {                             // mirrored tile
                us4 pk4 = { sv[0], sv[1], sv[2], sv[3] };      // 4 consecutive rows
                *(us4*)&C[(size_t)c * NROWS + rb] = pk4;       // 8B store
            }
        }
        // row maxima: reduce over the 16 lanes (m) of each quad
        #pragma unroll
        for (int reg = 0; reg < 4; ++reg) {
            u32 k = rmk[reg];
            k = max(k, (u32)__shfl_xor((int)k, 1));
            k = max(k, (u32)__shfl_xor((int)k, 2));
            k = max(k, (u32)__shfl_xor((int)k, 4));
            k = max(k, (u32)__shfl_xor((int)k, 8));
            if (m == 0) {
                int grw = row0 + by * 128 + wr * 64 + i * 16 + q * 4 + reg;
                M[(size_t)grw * 128 + bx * 2 + wc] = (ushort)k;
            }
        }
    }
    if (TRI && bx != by) {
        // col maxima (mirror rows): reduce over the 4 quads (q)
        #pragma unroll
        for (int j = 0; j < 4; ++j) {
            u32 k = cmk[j];
            k = max(k, (u32)__shfl_xor((int)k, 16));
            k = max(k, (u32)__shfl_xor((int)k, 32));
            if (q == 0) {
                int gc = gcol0 + wc * 64 + j * 16 + m;
                M[(size_t)gc * 128 + by * 2 + wr] = (ushort)k;
            }
        }
    }
}

// ---------------- select: ballot-bsearch top-20 + BCE (no shuffle loops) -----
// T = 20th-largest segment max (multiplicity) via 16-step ballot bsearch ->
// guaranteed >=20 elements >= T. Scan survivors (8 lanes/segment, uint4 each),
// compact to LDS. V20 = exact 20th element via ballot bsearch over survivors.
// Sum BCE over keys > V20 (+ ties at V20) in parallel; one final 6-shfl reduce.
__global__ __launch_bounds__(256) void k_select(const ushort* __restrict__ C,
                                                const ushort* __restrict__ M,
                                                const int* __restrict__ labels,
                                                int row0,
                                                float* __restrict__ partials) {
    __shared__ u32 s_surv[4][NSURV];
    __shared__ u32 s_cnt[4];
    int lane = threadIdx.x & 63;
    int wv   = threadIdx.x >> 6;
    int prow = blockIdx.x * 4 + wv;
    int grow = row0 + prow;
    const ushort* rowC = C + (size_t)prow * NROWS;

    if (lane == 0) s_cnt[wv] = 0;
    __syncthreads();

    // segment maxima (mono keys): lane holds segs 2*lane, 2*lane+1
    u32 pm  = *(const u32*)&M[(size_t)grow * 128 + 2 * lane];
    u32 klo = pm & 0xFFFFu, khi = pm >> 16;

    // T = largest 16-bit value with count(seg_max >= T) >= KSEL
    u32 T = 0;
    #pragma unroll
    for (int b = 15; b >= 0; --b) {
        u32 cand = T | (1u << b);
        int c = __popcll(__ballot(klo >= cand)) + __popcll(__ballot(khi >= cand));
        if (c >= KSEL) T = cand;
    }

    u64 rm0 = __ballot(klo >= T);    // segment 2*lane
    u64 rm1 = __ballot(khi >= T);    // segment 2*lane+1
    int nseg = __popcll(rm0) + __popcll(rm1);
    int sub = lane & 7, grp = lane >> 3;

    // scan rounds of up to 32 segments: 4 batches x (8 lanes/segment, uint4 ea)
    while (nseg > 0) {
        int ms[4] = {-1, -1, -1, -1};
        #pragma unroll
        for (int t = 0; t < 4; ++t) {
            #pragma unroll
            for (int g = 0; g < 8; ++g) {
                int seg = -1;
                if (rm0) { int b = __builtin_ctzll(rm0); seg = 2 * b;     rm0 &= rm0 - 1; }
                else if (rm1) { int b = __builtin_ctzll(rm1); seg = 2 * b + 1; rm1 &= rm1 - 1; }
                if (grp == g) ms[t] = seg;
            }
        }
        uint4 vv[4];
        #pragma unroll
        for (int t = 0; t < 4; ++t) {
            if (ms[t] >= 0) vv[t] = *(const uint4*)(rowC + ms[t] * 64 + sub * 8);
        }
        #pragma unroll
        for (int t = 0; t < 4; ++t) {
            if (ms[t] < 0) continue;
            u32 wds[4] = { vv[t].x, vv[t].y, vv[t].z, vv[t].w };
            u32 cbase = (u32)(ms[t] * 64 + sub * 8);
            #pragma unroll
            for (int h = 0; h < 4; ++h) {
                u32 w  = wds[h];
                u32 kA = mono16(w & 0xFFFFu);
                u32 kB = mono16(w >> 16);
                if (kA >= T) { u32 p = atomicAdd(&s_cnt[wv], 1u); if (p < NSURV) s_surv[wv][p] = (kA << 16) | (cbase + 2u * h); }
                if (kB >= T) { u32 p = atomicAdd(&s_cnt[wv], 1u); if (p < NSURV) s_surv[wv][p] = (kB << 16) | (cbase + 2u * h + 1u); }
            }
        }
        nseg -= 32;
    }

    u32 cnt = min(s_cnt[wv], (u32)NSURV);     // same-wave LDS: ordered
    u32 g[8];
    #pragma unroll
    for (int j = 0; j < 8; ++j) {
        u32 idx = (u32)lane + (u32)j * 64u;
        g[j] = (idx < cnt) ? s_surv[wv][idx] : 0u;
    }

    // V20 = exact 20th-largest element key (largest v with count(>=v) >= 20)
    u32 V = 0;
    #pragma unroll
    for (int b = 15; b >= 0; --b) {
        u32 cand = V | (1u << b);
        int c = 0;
        #pragma unroll
        for (int j = 0; j < 8; ++j)
            c += __popcll(__ballot((g[j] >> 16) >= cand));
        if (c >= KSEL) V = cand;
    }
    int cgt = 0, ceq = 0;
    #pragma unroll
    for (int j = 0; j < 8; ++j) {
        cgt += __popcll(__ballot(g[j] != 0 && (g[j] >> 16) > V));
        ceq += __popcll(__ballot(g[j] != 0 && (g[j] >> 16) == V));
    }
    int need = KSEL - cgt;                    // >= 1; ceq >= need guaranteed
    bool all_ties = (ceq == need);            // common case: tie set fits exactly

    int mylab = labels[grow];
    float loss = 0.0f;
    #pragma unroll
    for (int j = 0; j < 8; ++j) {
        u32 key = g[j] >> 16, col = g[j] & 0xFFFFu;
        if (g[j] != 0 && (key > V || (all_ties && key == V))) {
            u32 raw = (key & 0x8000u) ? (key ^ 0x8000u) : (key ^ 0xFFFFu);
            float v = __uint_as_float(raw << 16);
            float p = (v + 1.0f) * 0.5f;
            bool tm = (labels[col] == mylab);
            loss -= tm ? fmaxf(logf(p), -100.0f) : fmaxf(log1pf(-p), -100.0f);
        }
    }
    if (!all_ties) {
        // rare: more ties than slots -> pick `need` by descending col (matches
        // rounds 1-4's (key<<16|col)-max order, which validated at absmax 0.0)
        for (int r = 0; r < need; ++r) {
            u32 best = 0;
            #pragma unroll
            for (int j = 0; j < 8; ++j) {
                u32 c2 = (g[j] != 0 && (g[j] >> 16) == V) ? ((g[j] & 0xFFFFu) + 1u) : 0u;
                best = max(best, c2);
            }
            #pragma unroll
            for (int off = 32; off; off >>= 1) best = max(best, (u32)__shfl_xor((int)best, off));
            #pragma unroll
            for (int j = 0; j < 8; ++j) {
                if (g[j] != 0 && (g[j] >> 16) == V && ((g[j] & 0xFFFFu) + 1u) == best) {
                    u32 col = g[j] & 0xFFFFu;
                    u32 raw = (V & 0x8000u) ? (V ^ 0x8000u) : (V ^ 0xFFFFu);
                    float v = __uint_as_float(raw << 16);
                    float p = (v + 1.0f) * 0.5f;
                    bool tm = (labels[col] == mylab);
                    loss -= tm ? fmaxf(logf(p), -100.0f) : fmaxf(log1pf(-p), -100.0f);
                    g[j] = 0;
                }
            }
        }
    }

    #pragma unroll
    for (int off = 32; off; off >>= 1) loss += __shfl_xor(loss, off);
    if (lane == 0) partials[grow] = loss;
}

__global__ __launch_bounds__(256) void k_final(const float* __restrict__ partials,
                                               float* __restrict__ out) {
    __shared__ float s[4];
    int tid = threadIdx.x, lane = tid & 63, wvi = tid >> 6;
    const float4* p4 = (const float4*)partials;
    float sum = 0.0f;
    #pragma unroll
    for (int i = 0; i < 8; ++i) {
        float4 v = p4[tid + i * 256];
        sum += v.x + v.y + v.z + v.w;
    }
    #pragma unroll
    for (int off = 32; off; off >>= 1) sum += __shfl_xor(sum, off);
    if (lane == 0) s[wvi] = sum;
    __syncthreads();
    if (tid == 0) out[0] = (s[0] + s[1] + s[2] + s[3]) * (1.0f / (float)(NROWS * KSEL));
}

extern "C" void kernel_launch(void* const* d_in, const int* in_sizes, int n_in,
                              void* d_out, int out_size, void* d_ws, size_t ws_size,
                              hipStream_t stream) {
    const float* batch  = (const float*)d_in[0];
    const int*   labels = (const int*)d_in[1];

    ushort* xn = (ushort*)d_ws;
    ushort* C  = xn + (size_t)NROWS * DIM;
    // M (2 MB) and partials (32 KB) live in the batch input buffer (16 MB):
    // batch is fully consumed by k_norm before k_gemm/k_select write them.
    ushort* M        = (ushort*)d_in[0];
    float*  partials = (float*)((char*)d_in[0] + (4u << 20));

    size_t need_full = (size_t)NROWS * DIM * 2 + (size_t)NROWS * NROWS * 2;

    k_norm<<<NROWS / 4, 256, 0, stream>>>(batch, xn);

    if (ws_size >= need_full) {
        // full symmetric path: 2080 lower-triangle blocks, one select pass
        k_gemm<true><<<dim3(64 * 65 / 2), 256, 0, stream>>>(xn, C, M, 0);
        k_select<<<NROWS / 4, 256, 0, stream>>>(C, M, labels, 0, partials);
    } else {
        // fallback: panel path (24 MB of ws)
        for (int p = 0; p < NROWS / PANEL; ++p) {
            k_gemm<false><<<dim3(64, PANEL / 128), 256, 0, stream>>>(xn, C, M, p * PANEL);
            k_select<<<PANEL / 4, 256, 0, stream>>>(C, M, labels, p * PANEL, partials);
        }
    }
    k_final<<<1, 256, 0, stream>>>(partials, (float*)d_out);
}

// Round 6
// 166.718 us; speedup vs baseline: 1.7497x; 1.0751x over previous
//
#include <hip/hip_runtime.h>
#include <hip/hip_bf16.h>

#define NROWS 8192
#define DIM   512
#define KSEL  20
#define PANEL 1024
#define NSURV 512

typedef unsigned int u32;
typedef unsigned long long u64;
typedef short bf16x8 __attribute__((ext_vector_type(8)));
typedef float f32x4 __attribute__((ext_vector_type(4)));
typedef ushort u16x2 __attribute__((ext_vector_type(2)));

typedef const void __attribute__((address_space(1))) as1_void;
typedef void __attribute__((address_space(3))) as3_void;

__device__ __forceinline__ void async_ld16(const ushort* g, ushort* l) {
    __builtin_amdgcn_global_load_lds((as1_void*)g, (as3_void*)l, 16, 0, 0);
}

// round-to-nearest-even f32 -> bf16 bits
__device__ __forceinline__ ushort f2bf(float f) {
    u32 u = __float_as_uint(f);
    return (ushort)((u + 0x7FFFu + ((u >> 16) & 1u)) >> 16);
}

// monotone map for one u16 bf16 pattern: integer compare == float compare
__device__ __forceinline__ u32 mono16(u32 r) {
    return r ^ (0x8000u | ((r >> 15) * 0x7FFFu));
}

__device__ __forceinline__ u32 mkey(float f) { return mono16((u32)f2bf(f)); }

// packed u16x2 max
__device__ __forceinline__ u32 pkmax(u32 a, u32 b) {
    union { u32 u; u16x2 v; } x, y; x.u = a; y.u = b;
    x.v = __builtin_elementwise_max(x.v, y.v);
    return x.u;
}

// swizzled tile index: (r,c) in 128x128, 8-col chunks XOR-rotated by (r>>3)
// -> b128 row reads stay contiguous; transposed u16 reads spread banks.
__device__ __forceinline__ int tix(int r, int c) {
    return r * 128 + ((c & 7) | ((((c >> 3) ^ (r >> 3)) & 15) << 3));
}

// ---------------- normalize: fp32 rows -> unit-norm bf16 rows ----------------
__global__ __launch_bounds__(256) void k_norm(const float* __restrict__ x,
                                              ushort* __restrict__ xn) {
    int lane = threadIdx.x & 63;
    int wv   = threadIdx.x >> 6;
    int row  = blockIdx.x * 4 + wv;
    const float4* xr = (const float4*)(x + (size_t)row * DIM);
    float4 a = xr[2 * lane];
    float4 b = xr[2 * lane + 1];
    float ss = a.x*a.x + a.y*a.y + a.z*a.z + a.w*a.w
             + b.x*b.x + b.y*b.y + b.z*b.z + b.w*b.w;
    #pragma unroll
    for (int off = 32; off; off >>= 1) ss += __shfl_xor(ss, off);
    float sc = 1.0f / fmaxf(sqrtf(ss), 1e-12f);
    float v[8] = {a.x*sc, a.y*sc, a.z*sc, a.w*sc, b.x*sc, b.y*sc, b.z*sc, b.w*sc};
    union { ushort u[8]; uint4 q; } o;
    #pragma unroll
    for (int i = 0; i < 8; ++i) o.u[i] = f2bf(v[i]);
    *(uint4*)(xn + (size_t)row * DIM + lane * 8) = o.q;
}

// ---------------- GEMM: C = Xn * Xn^T (bf16 out), diag = -3.0 ----------------
// 128x128 tile, 4 waves (2x2), each wave 4x4 subtiles of 16x16x32 bf16 MFMA.
// TRI=true: 2080 lower-triangle blocks (bx<=by); each writes its tile AND the
// mirrored transpose -> full symmetric C at half FLOPs. Epilogue stages the
// tile in LDS (reusing the staging buffers) for coalesced dwordx4 stores of
// both orientations, and emits per-(row,64-col-seg) maxima into M[NROWS][128].
template<bool TRI>
__global__ __launch_bounds__(256) void k_gemm(const ushort* __restrict__ xn,
                                              ushort* __restrict__ C,
                                              ushort* __restrict__ M,
                                              int row0) {
    __shared__ ushort sh[2 * 128 * 64];      // K-loop: A|B staging; epi: 128x128 tile
    ushort* lA = sh;
    ushort* lB = sh + 128 * 64;
    int tid  = threadIdx.x;
    int lane = tid & 63, wv = tid >> 6;
    int wr = wv >> 1, wc = wv & 1;
    int q = lane >> 4, m = lane & 15;
    int bx, by;
    if (TRI) {
        int t = blockIdx.x;
        by = (int)((sqrtf(8.0f * (float)t + 1.0f) - 1.0f) * 0.5f);
        while ((by + 1) * (by + 2) / 2 <= t) ++by;
        while (by * (by + 1) / 2 > t) --by;
        bx = t - by * (by + 1) / 2;          // bx <= by
    } else {
        bx = blockIdx.x; by = blockIdx.y;
    }
    int grow0 = row0 + by * 128;   // A rows (global)
    int gcol0 = bx * 128;          // B rows = C cols (global)
    f32x4 acc[4][4] = {};

    int lr = lane >> 3;   // row within 8-row group
    int lc = lane & 7;    // LDS chunk slot this lane fills
    for (int kc = 0; kc < 8; ++kc) {
        #pragma unroll
        for (int t = 0; t < 4; ++t) {
            int rb  = wv * 32 + t * 8;     // wave-uniform row base
            int r   = rb + lr;
            int fch = lc ^ (r & 7);        // XOR chunk swizzle (bank-conflict-free)
            async_ld16(xn + (size_t)(grow0 + r) * DIM + kc * 64 + fch * 8, &lA[rb * 64]);
            async_ld16(xn + (size_t)(gcol0 + r) * DIM + kc * 64 + fch * 8, &lB[rb * 64]);
        }
        __syncthreads();
        #pragma unroll
        for (int s = 0; s < 2; ++s) {
            bf16x8 af[4], bfr[4];
            #pragma unroll
            for (int i = 0; i < 4; ++i) {
                int ra = wr * 64 + i * 16 + m;
                af[i]  = *(const bf16x8*)&lA[ra * 64 + (((s * 4 + q) ^ (ra & 7)) * 8)];
                int rb2 = wc * 64 + i * 16 + m;
                bfr[i] = *(const bf16x8*)&lB[rb2 * 64 + (((s * 4 + q) ^ (rb2 & 7)) * 8)];
            }
            #pragma unroll
            for (int i = 0; i < 4; ++i)
                #pragma unroll
                for (int j = 0; j < 4; ++j)
                    acc[i][j] = __builtin_amdgcn_mfma_f32_16x16x32_bf16(af[i], bfr[j], acc[i][j], 0, 0, 0);
        }
        __syncthreads();
    }

    // ---- epilogue phase 1: stage tile into LDS + M digest (fp32 maxima) ----
    // C/D layout: col=lane&15, row=quad*4+reg (m89/m91-verified)
    float cmf[4] = {-3.0f, -3.0f, -3.0f, -3.0f};     // per-j col maxima
    #pragma unroll
    for (int i = 0; i < 4; ++i) {
        float rmf[4] = {-3.0f, -3.0f, -3.0f, -3.0f}; // per-reg row maxima
        int rloc = wr * 64 + i * 16 + q * 4;         // local row base (0..127)
        #pragma unroll
        for (int j = 0; j < 4; ++j) {
            int cl = wc * 64 + j * 16 + m;           // local col
            int c  = gcol0 + cl;                     // global col
            #pragma unroll
            for (int reg = 0; reg < 4; ++reg) {
                int grw  = row0 + by * 128 + rloc + reg;
                float a  = acc[i][j][reg];
                bool dg  = (grw == c);
                float mv = dg ? -3.0f : a;
                rmf[reg] = fmaxf(rmf[reg], mv);
                cmf[j]   = fmaxf(cmf[j], mv);
                sh[tix(rloc + reg, cl)] = dg ? (ushort)0xC040 : f2bf(a);
            }
        }
        // row maxima: packed 2-rows/u32, reduce over 16 lanes (m) of each quad
        u32 p01 = mkey(rmf[0]) | (mkey(rmf[1]) << 16);
        u32 p23 = mkey(rmf[2]) | (mkey(rmf[3]) << 16);
        #pragma unroll
        for (int off = 1; off <= 8; off <<= 1) {
            p01 = pkmax(p01, (u32)__shfl_xor((int)p01, off));
            p23 = pkmax(p23, (u32)__shfl_xor((int)p23, off));
        }
        if (m == 0) {
            size_t mb = (size_t)(row0 + by * 128 + rloc) * 128 + bx * 2 + wc;
            M[mb]       = (ushort)(p01 & 0xFFFFu);
            M[mb + 128] = (ushort)(p01 >> 16);
            M[mb + 256] = (ushort)(p23 & 0xFFFFu);
            M[mb + 384] = (ushort)(p23 >> 16);
        }
    }
    if (TRI && bx != by) {
        // col maxima (mirror rows): packed 2-cols/u32, reduce over quads (q)
        u32 q01 = mkey(cmf[0]) | (mkey(cmf[1]) << 16);
        u32 q23 = mkey(cmf[2]) | (mkey(cmf[3]) << 16);
        q01 = pkmax(q01, (u32)__shfl_xor((int)q01, 16));
        q01 = pkmax(q01, (u32)__shfl_xor((int)q01, 32));
        q23 = pkmax(q23, (u32)__shfl_xor((int)q23, 16));
        q23 = pkmax(q23, (u32)__shfl_xor((int)q23, 32));
        if (q == 0) {
            int gc = gcol0 + wc * 64 + m;
            int sg = by * 2 + wr;
            M[(size_t)(gc +  0) * 128 + sg] = (ushort)(q01 & 0xFFFFu);
            M[(size_t)(gc + 16) * 128 + sg] = (ushort)(q01 >> 16);
            M[(size_t)(gc + 32) * 128 + sg] = (ushort)(q23 & 0xFFFFu);
            M[(size_t)(gc + 48) * 128 + sg] = (ushort)(q23 >> 16);
        }
    }
    __syncthreads();

    // ---- epilogue phase 2: coalesced readback & stores ----
    int tr = tid >> 4;       // 0..15
    int tc = tid & 15;       // chunk / row-group
    #pragma unroll
    for (int p = 0; p < 8; ++p) {
        int r = p * 16 + tr;
        uint4 v = *(const uint4*)&sh[r * 128 + (((tc ^ ((r >> 3) & 15))) << 3)];
        *(uint4*)&C[(size_t)(by * 128 + r) * NROWS + gcol0 + tc * 8] = v;
    }
    if (TRI && bx != by) {
        #pragma unroll
        for (int p = 0; p < 8; ++p) {
            int ct = p * 16 + tr;
            int r8 = tc * 8;
            u32 aw[8];
            #pragma unroll
            for (int k = 0; k < 8; ++k)
                aw[k] = (u32)sh[tix(r8 + k, ct)];
            uint4 o = { aw[0] | (aw[1] << 16), aw[2] | (aw[3] << 16),
                        aw[4] | (aw[5] << 16), aw[6] | (aw[7] << 16) };
            *(uint4*)&C[(size_t)(gcol0 + ct) * NROWS + by * 128 + r8] = o;
        }
    }
}

// ---------------- select: ballot-bsearch top-20 + BCE ------------------------
__global__ __launch_bounds__(256) void k_select(const ushort* __restrict__ C,
                                                const ushort* __restrict__ M,
                                                const int* __restrict__ labels,
                                                int row0,
                                                float* __restrict__ partials) {
    __shared__ u32 s_surv[4][NSURV];
    __shared__ u32 s_cnt[4];
    int lane = threadIdx.x & 63;
    int wv   = threadIdx.x >> 6;
    int prow = blockIdx.x * 4 + wv;
    int grow = row0 + prow;
    const ushort* rowC = C + (size_t)prow * NROWS;

    if (lane == 0) s_cnt[wv] = 0;
    __syncthreads();

    // segment maxima (mono keys): lane holds segs 2*lane, 2*lane+1
    u32 pm  = *(const u32*)&M[(size_t)grow * 128 + 2 * lane];
    u32 klo = pm & 0xFFFFu, khi = pm >> 16;

    // T = largest 16-bit value with count(seg_max >= T) >= KSEL
    u32 T = 0;
    #pragma unroll
    for (int b = 15; b >= 0; --b) {
        u32 cand = T | (1u << b);
        int c = __popcll(__ballot(klo >= cand)) + __popcll(__ballot(khi >= cand));
        if (c >= KSEL) T = cand;
    }

    u64 rm0 = __ballot(klo >= T);    // segment 2*lane
    u64 rm1 = __ballot(khi >= T);    // segment 2*lane+1
    int nseg = __popcll(rm0) + __popcll(rm1);
    int sub = lane & 7, grp = lane >> 3;

    // scan rounds of up to 32 segments: 4 batches x (8 lanes/segment, uint4 ea)
    while (nseg > 0) {
        int ms[4] = {-1, -1, -1, -1};
        #pragma unroll
        for (int t = 0; t < 4; ++t) {
            #pragma unroll
            for (int g = 0; g < 8; ++g) {
                int seg = -1;
                if (rm0) { int b = __builtin_ctzll(rm0); seg = 2 * b;     rm0 &= rm0 - 1; }
                else if (rm1) { int b = __builtin_ctzll(rm1); seg = 2 * b + 1; rm1 &= rm1 - 1; }
                if (grp == g) ms[t] = seg;
            }
        }
        uint4 vv[4];
        #pragma unroll
        for (int t = 0; t < 4; ++t) {
            if (ms[t] >= 0) vv[t] = *(const uint4*)(rowC + ms[t] * 64 + sub * 8);
        }
        #pragma unroll
        for (int t = 0; t < 4; ++t) {
            if (ms[t] < 0) continue;
            u32 wds[4] = { vv[t].x, vv[t].y, vv[t].z, vv[t].w };
            u32 cbase = (u32)(ms[t] * 64 + sub * 8);
            #pragma unroll
            for (int h = 0; h < 4; ++h) {
                u32 w  = wds[h];
                u32 kA = mono16(w & 0xFFFFu);
                u32 kB = mono16(w >> 16);
                if (kA >= T) { u32 p = atomicAdd(&s_cnt[wv], 1u); if (p < NSURV) s_surv[wv][p] = (kA << 16) | (cbase + 2u * h); }
                if (kB >= T) { u32 p = atomicAdd(&s_cnt[wv], 1u); if (p < NSURV) s_surv[wv][p] = (kB << 16) | (cbase + 2u * h + 1u); }
            }
        }
        nseg -= 32;
    }

    u32 cnt = min(s_cnt[wv], (u32)NSURV);     // same-wave LDS: ordered
    int mylab = labels[grow];
    float loss = 0.0f;

    if (cnt <= 64u) {
        // fast path: one survivor per lane; V20 bsearch = 16 ballots
        u32 gg  = ((u32)lane < cnt) ? s_surv[wv][lane] : 0u;
        u32 key = gg >> 16;
        u32 V = 0;
        #pragma unroll
        for (int b = 15; b >= 0; --b) {
            u32 cand = V | (1u << b);
            if (__popcll(__ballot(key >= cand)) >= KSEL) V = cand;
        }
        int cgt  = __popcll(__ballot(key > V));
        int ceq  = __popcll(__ballot(gg != 0 && key == V));
        int need = KSEL - cgt;
        bool incl;
        if (ceq == need) {
            incl = (gg != 0) && (key >= V);
        } else {
            // more ties than slots: take `need` largest cols among ties
            // (matches prior rounds' (key<<16|col)-descending order)
            u32 col = gg & 0xFFFFu;
            bool tie = (gg != 0) && (key == V);
            u32 Cv = 0;
            #pragma unroll
            for (int b = 15; b >= 0; --b) {
                u32 cand2 = Cv | (1u << b);
                if (__popcll(__ballot(tie && col >= cand2)) >= need) Cv = cand2;
            }
            incl = (key > V) || (tie && col >= Cv);   // cols unique -> exact
        }
        if (incl) {
            u32 col = gg & 0xFFFFu;
            u32 raw = (key & 0x8000u) ? (key ^ 0x8000u) : (key ^ 0xFFFFu);
            float v = __uint_as_float(raw << 16);
            float p = (v + 1.0f) * 0.5f;
            bool tm = (labels[col] == mylab);
            loss -= tm ? fmaxf(logf(p), -100.0f) : fmaxf(log1pf(-p), -100.0f);
        }
    } else {
        // fallback (rare): 8 survivors per lane
        u32 g[8];
        #pragma unroll
        for (int j = 0; j < 8; ++j) {
            u32 idx = (u32)lane + (u32)j * 64u;
            g[j] = (idx < cnt) ? s_surv[wv][idx] : 0u;
        }
        u32 V = 0;
        #pragma unroll
        for (int b = 15; b >= 0; --b) {
            u32 cand = V | (1u << b);
            int c = 0;
            #pragma unroll
            for (int j = 0; j < 8; ++j)
                c += __popcll(__ballot((g[j] >> 16) >= cand));
            if (c >= KSEL) V = cand;
        }
        int cgt = 0, ceq = 0;
        #pragma unroll
        for (int j = 0; j < 8; ++j) {
            cgt += __popcll(__ballot(g[j] != 0 && (g[j] >> 16) > V));
            ceq += __popcll(__ballot(g[j] != 0 && (g[j] >> 16) == V));
        }
        int need = KSEL - cgt;
        bool all_ties = (ceq == need);
        #pragma unroll
        for (int j = 0; j < 8; ++j) {
            u32 key = g[j] >> 16, col = g[j] & 0xFFFFu;
            if (g[j] != 0 && (key > V || (all_ties && key == V))) {
                u32 raw = (key & 0x8000u) ? (key ^ 0x8000u) : (key ^ 0xFFFFu);
                float v = __uint_as_float(raw << 16);
                float p = (v + 1.0f) * 0.5f;
                bool tm = (labels[col] == mylab);
                loss -= tm ? fmaxf(logf(p), -100.0f) : fmaxf(log1pf(-p), -100.0f);
            }
        }
        if (!all_ties) {
            for (int r = 0; r < need; ++r) {
                u32 best = 0;
                #pragma unroll
                for (int j = 0; j < 8; ++j) {
                    u32 c2 = (g[j] != 0 && (g[j] >> 16) == V) ? ((g[j] & 0xFFFFu) + 1u) : 0u;
                    best = max(best, c2);
                }
                #pragma unroll
                for (int off = 32; off; off >>= 1) best = max(best, (u32)__shfl_xor((int)best, off));
                #pragma unroll
                for (int j = 0; j < 8; ++j) {
                    if (g[j] != 0 && (g[j] >> 16) == V && ((g[j] & 0xFFFFu) + 1u) == best) {
                        u32 col = g[j] & 0xFFFFu;
                        u32 raw = (V & 0x8000u) ? (V ^ 0x8000u) : (V ^ 0xFFFFu);
                        float v = __uint_as_float(raw << 16);
                        float p = (v + 1.0f) * 0.5f;
                        bool tm = (labels[col] == mylab);
                        loss -= tm ? fmaxf(logf(p), -100.0f) : fmaxf(log1pf(-p), -100.0f);
                        g[j] = 0;
                    }
                }
            }
        }
    }

    #pragma unroll
    for (int off = 32; off; off >>= 1) loss += __shfl_xor(loss, off);
    if (lane == 0) partials[grow] = loss;
}

__global__ __launch_bounds__(256) void k_final(const float* __restrict__ partials,
                                               float* __restrict__ out) {
    __shared__ float s[4];
    int tid = threadIdx.x, lane = tid & 63, wvi = tid >> 6;
    const float4* p4 = (const float4*)partials;
    float sum = 0.0f;
    #pragma unroll
    for (int i = 0; i < 8; ++i) {
        float4 v = p4[tid + i * 256];
        sum += v.x + v.y + v.z + v.w;
    }
    #pragma unroll
    for (int off = 32; off; off >>= 1) sum += __shfl_xor(sum, off);
    if (lane == 0) s[wvi] = sum;
    __syncthreads();
    if (tid == 0) out[0] = (s[0] + s[1] + s[2] + s[3]) * (1.0f / (float)(NROWS * KSEL));
}

extern "C" void kernel_launch(void* const* d_in, const int* in_sizes, int n_in,
                              void* d_out, int out_size, void* d_ws, size_t ws_size,
                              hipStream_t stream) {
    const float* batch  = (const float*)d_in[0];
    const int*   labels = (const int*)d_in[1];

    ushort* xn = (ushort*)d_ws;
    ushort* C  = xn + (size_t)NROWS * DIM;
    // M (2 MB) and partials (32 KB) live in the batch input buffer (16 MB):
    // batch is fully consumed by k_norm before k_gemm/k_select write them.
    ushort* M        = (ushort*)d_in[0];
    float*  partials = (float*)((char*)d_in[0] + (4u << 20));

    size_t need_full = (size_t)NROWS * DIM * 2 + (size_t)NROWS * NROWS * 2;

    k_norm<<<NROWS / 4, 256, 0, stream>>>(batch, xn);

    if (ws_size >= need_full) {
        // full symmetric path: 2080 lower-triangle blocks, one select pass
        k_gemm<true><<<dim3(64 * 65 / 2), 256, 0, stream>>>(xn, C, M, 0);
        k_select<<<NROWS / 4, 256, 0, stream>>>(C, M, labels, 0, partials);
    } else {
        // fallback: panel path (24 MB of ws)
        for (int p = 0; p < NROWS / PANEL; ++p) {
            k_gemm<false><<<dim3(64, PANEL / 128), 256, 0, stream>>>(xn, C, M, p * PANEL);
            k_select<<<PANEL / 4, 256, 0, stream>>>(C, M, labels, p * PANEL, partials);
        }
    }
    k_final<<<1, 256, 0, stream>>>(partials, (float*)d_out);
}

// Round 7
// 162.307 us; speedup vs baseline: 1.7972x; 1.0272x over previous
//
#include <hip/hip_runtime.h>
#include <hip/hip_bf16.h>

#define NROWS 8192
#define DIM   512
#define KSEL  20
#define PANEL 1024
#define NSURV 512

typedef unsigned int u32;
typedef unsigned long long u64;
typedef short bf16x8 __attribute__((ext_vector_type(8)));
typedef float f32x4 __attribute__((ext_vector_type(4)));
typedef ushort u16x2 __attribute__((ext_vector_type(2)));

typedef const void __attribute__((address_space(1))) as1_void;
typedef void __attribute__((address_space(3))) as3_void;

__device__ __forceinline__ void async_ld16(const ushort* g, ushort* l) {
    __builtin_amdgcn_global_load_lds((as1_void*)g, (as3_void*)l, 16, 0, 0);
}

// round-to-nearest-even f32 -> bf16 bits
__device__ __forceinline__ ushort f2bf(float f) {
    u32 u = __float_as_uint(f);
    return (ushort)((u + 0x7FFFu + ((u >> 16) & 1u)) >> 16);
}

// monotone map for one u16 bf16 pattern: integer compare == float compare
__device__ __forceinline__ u32 mono16(u32 r) {
    return r ^ (0x8000u | ((r >> 15) * 0x7FFFu));
}

__device__ __forceinline__ u32 mkey(float f) { return mono16((u32)f2bf(f)); }

// packed u16x2 max
__device__ __forceinline__ u32 pkmax(u32 a, u32 b) {
    union { u32 u; u16x2 v; } x, y; x.u = a; y.u = b;
    x.v = __builtin_elementwise_max(x.v, y.v);
    return x.u;
}

// ---------------- normalize: fp32 rows -> unit-norm bf16 rows ----------------
__global__ __launch_bounds__(256) void k_norm(const float* __restrict__ x,
                                              ushort* __restrict__ xn) {
    int lane = threadIdx.x & 63;
    int wv   = threadIdx.x >> 6;
    int row  = blockIdx.x * 4 + wv;
    const float4* xr = (const float4*)(x + (size_t)row * DIM);
    float4 a = xr[2 * lane];
    float4 b = xr[2 * lane + 1];
    float ss = a.x*a.x + a.y*a.y + a.z*a.z + a.w*a.w
             + b.x*b.x + b.y*b.y + b.z*b.z + b.w*b.w;
    #pragma unroll
    for (int off = 32; off; off >>= 1) ss += __shfl_xor(ss, off);
    float sc = 1.0f / fmaxf(sqrtf(ss), 1e-12f);
    float v[8] = {a.x*sc, a.y*sc, a.z*sc, a.w*sc, b.x*sc, b.y*sc, b.z*sc, b.w*sc};
    union { ushort u[8]; uint4 q; } o;
    #pragma unroll
    for (int i = 0; i < 8; ++i) o.u[i] = f2bf(v[i]);
    *(uint4*)(xn + (size_t)row * DIM + lane * 8) = o.q;
}

// ---------------- GEMM: C = Xn * Xn^T (bf16 out), diag = -3.0 ----------------
// 128x128 tile, 4 waves (2x2), each wave 4x4 subtiles of 16x16x32 bf16 MFMA.
// TRI=true: 2080 lower-triangle blocks (bx<=by); each writes its tile AND the
// mirrored transpose. Epilogue: (1) stage row-tile in LDS with a dword-XOR
// swizzle D = r*64 + (cd ^ (q(r)<<3)), q(r)=(r>>2)&3 -> phase-1 scalar writes
// are conflict-free (octet from j^q, offset from m>>1) and phase-2 b128 row
// reads stay contiguous; (2) for mirror, re-stage the SAME 32KB as a
// transposed tile via packed row-pair b32 writes, then coalesced b128 reads.
template<bool TRI>
__global__ __launch_bounds__(256) void k_gemm(const ushort* __restrict__ xn,
                                              ushort* __restrict__ C,
                                              ushort* __restrict__ M,
                                              int row0) {
    __shared__ ushort sh[128 * 128];         // K-loop: A|B staging; epi: tile
    ushort* lA = sh;
    ushort* lB = sh + 128 * 64;
    int tid  = threadIdx.x;
    int lane = tid & 63, wv = tid >> 6;
    int wr = wv >> 1, wc = wv & 1;
    int q = lane >> 4, m = lane & 15;
    int bx, by;
    if (TRI) {
        int t = blockIdx.x;
        by = (int)((sqrtf(8.0f * (float)t + 1.0f) - 1.0f) * 0.5f);
        while ((by + 1) * (by + 2) / 2 <= t) ++by;
        while (by * (by + 1) / 2 > t) --by;
        bx = t - by * (by + 1) / 2;          // bx <= by
    } else {
        bx = blockIdx.x; by = blockIdx.y;
    }
    int grow0 = row0 + by * 128;   // A rows (global)
    int gcol0 = bx * 128;          // B rows = C cols (global)
    f32x4 acc[4][4] = {};

    int lr = lane >> 3;   // row within 8-row group
    int lc = lane & 7;    // LDS chunk slot this lane fills
    for (int kc = 0; kc < 8; ++kc) {
        #pragma unroll
        for (int t = 0; t < 4; ++t) {
            int rb  = wv * 32 + t * 8;     // wave-uniform row base
            int r   = rb + lr;
            int fch = lc ^ (r & 7);        // XOR chunk swizzle (bank-conflict-free)
            async_ld16(xn + (size_t)(grow0 + r) * DIM + kc * 64 + fch * 8, &lA[rb * 64]);
            async_ld16(xn + (size_t)(gcol0 + r) * DIM + kc * 64 + fch * 8, &lB[rb * 64]);
        }
        __syncthreads();
        #pragma unroll
        for (int s = 0; s < 2; ++s) {
            bf16x8 af[4], bfr[4];
            #pragma unroll
            for (int i = 0; i < 4; ++i) {
                int ra = wr * 64 + i * 16 + m;
                af[i]  = *(const bf16x8*)&lA[ra * 64 + (((s * 4 + q) ^ (ra & 7)) * 8)];
                int rb2 = wc * 64 + i * 16 + m;
                bfr[i] = *(const bf16x8*)&lB[rb2 * 64 + (((s * 4 + q) ^ (rb2 & 7)) * 8)];
            }
            #pragma unroll
            for (int i = 0; i < 4; ++i)
                #pragma unroll
                for (int j = 0; j < 4; ++j)
                    acc[i][j] = __builtin_amdgcn_mfma_f32_16x16x32_bf16(af[i], bfr[j], acc[i][j], 0, 0, 0);
        }
        __syncthreads();
    }

    // ---- epilogue phase 1: stage row-tile into LDS + M digest ----
    // C/D layout: col=lane&15, row=quad*4+reg (m89/m91-verified)
    float cmf[4] = {-3.0f, -3.0f, -3.0f, -3.0f};     // per-j col maxima
    #pragma unroll
    for (int i = 0; i < 4; ++i) {
        float rmf[4] = {-3.0f, -3.0f, -3.0f, -3.0f}; // per-reg row maxima
        int rloc = wr * 64 + i * 16 + q * 4;         // local row base (0..127)
        #pragma unroll
        for (int j = 0; j < 4; ++j) {
            int cl = wc * 64 + j * 16 + m;           // local col
            int c  = gcol0 + cl;                     // global col
            #pragma unroll
            for (int reg = 0; reg < 4; ++reg) {
                int r    = rloc + reg;
                int grw  = row0 + by * 128 + r;
                float a  = acc[i][j][reg];
                bool dg  = (grw == c);
                float mv = dg ? -3.0f : a;
                rmf[reg] = fmaxf(rmf[reg], mv);
                cmf[j]   = fmaxf(cmf[j], mv);
                // dword-swizzled row-tile write (conflict-free; q=(r>>2)&3)
                int D = r * 64 + ((cl >> 1) ^ (q << 3));
                sh[D * 2 + (cl & 1)] = dg ? (ushort)0xC040 : f2bf(a);
            }
        }
        // row maxima: packed 2-rows/u32, reduce over 16 lanes (m) of each quad
        u32 p01 = mkey(rmf[0]) | (mkey(rmf[1]) << 16);
        u32 p23 = mkey(rmf[2]) | (mkey(rmf[3]) << 16);
        #pragma unroll
        for (int off = 1; off <= 8; off <<= 1) {
            p01 = pkmax(p01, (u32)__shfl_xor((int)p01, off));
            p23 = pkmax(p23, (u32)__shfl_xor((int)p23, off));
        }
        if (m == 0) {
            size_t mb = (size_t)(row0 + by * 128 + rloc) * 128 + bx * 2 + wc;
            M[mb]       = (ushort)(p01 & 0xFFFFu);
            M[mb + 128] = (ushort)(p01 >> 16);
            M[mb + 256] = (ushort)(p23 & 0xFFFFu);
            M[mb + 384] = (ushort)(p23 >> 16);
        }
    }
    if (TRI && bx != by) {
        // col maxima (mirror rows): packed 2-cols/u32, reduce over quads (q)
        u32 q01 = mkey(cmf[0]) | (mkey(cmf[1]) << 16);
        u32 q23 = mkey(cmf[2]) | (mkey(cmf[3]) << 16);
        q01 = pkmax(q01, (u32)__shfl_xor((int)q01, 16));
        q01 = pkmax(q01, (u32)__shfl_xor((int)q01, 32));
        q23 = pkmax(q23, (u32)__shfl_xor((int)q23, 16));
        q23 = pkmax(q23, (u32)__shfl_xor((int)q23, 32));
        if (q == 0) {
            int gc = gcol0 + wc * 64 + m;
            int sg = by * 2 + wr;
            M[(size_t)(gc +  0) * 128 + sg] = (ushort)(q01 & 0xFFFFu);
            M[(size_t)(gc + 16) * 128 + sg] = (ushort)(q01 >> 16);
            M[(size_t)(gc + 32) * 128 + sg] = (ushort)(q23 & 0xFFFFu);
            M[(size_t)(gc + 48) * 128 + sg] = (ushort)(q23 >> 16);
        }
    }
    __syncthreads();

    // ---- epilogue phase 2a: coalesced row-major readback & store ----
    int tr = tid >> 4;       // 0..15
    int tc = tid & 15;       // 8-col chunk
    #pragma unroll
    for (int p = 0; p < 8; ++p) {
        int r  = p * 16 + tr;
        int qr = (r >> 2) & 3;
        uint4 v = *(const uint4*)&sh[(r * 64 + ((tc * 4) ^ (qr << 3))) * 2];
        *(uint4*)&C[(size_t)(by * 128 + r) * NROWS + gcol0 + tc * 8] = v;
    }

    if (TRI && bx != by) {
        // ---- phase 2b: re-stage transposed tile (packed row-pair b32) ----
        __syncthreads();
        u32* sh32 = (u32*)sh;
        #pragma unroll
        for (int i = 0; i < 4; ++i) {
            int cd0 = wr * 32 + i * 8 + q * 2;       // C^T dword col (rows rloc..+1)
            #pragma unroll
            for (int j = 0; j < 4; ++j) {
                int rT = wc * 64 + j * 16 + m;       // C^T row = orig col
                int gT = ((rT >> 2) & 3) << 3;
                u32 w0 = (u32)f2bf(acc[i][j][0]) | ((u32)f2bf(acc[i][j][1]) << 16);
                u32 w1 = (u32)f2bf(acc[i][j][2]) | ((u32)f2bf(acc[i][j][3]) << 16);
                sh32[rT * 64 + (cd0 ^ gT)]       = w0;
                sh32[rT * 64 + ((cd0 + 1) ^ gT)] = w1;
            }
        }
        __syncthreads();
        // ---- phase 2c: coalesced transposed readback & store ----
        #pragma unroll
        for (int p = 0; p < 8; ++p) {
            int ct = p * 16 + tr;                    // mirror global row gcol0+ct
            int gq = ((ct >> 2) & 3) << 3;
            uint4 v = *(const uint4*)&sh32[ct * 64 + ((tc * 4) ^ gq)];
            *(uint4*)&C[(size_t)(gcol0 + ct) * NROWS + by * 128 + tc * 8] = v;
        }
    }
}

// ---------------- select: ballot-bsearch top-20 + BCE ------------------------
__global__ __launch_bounds__(256) void k_select(const ushort* __restrict__ C,
                                                const ushort* __restrict__ M,
                                                const int* __restrict__ labels,
                                                int row0,
                                                float* __restrict__ partials) {
    __shared__ u32 s_surv[4][NSURV];
    __shared__ u32 s_seg[4][128];
    __shared__ u32 s_cnt[4];
    __shared__ u32 s_scnt[4];
    int lane = threadIdx.x & 63;
    int wv   = threadIdx.x >> 6;
    int prow = blockIdx.x * 4 + wv;
    int grow = row0 + prow;
    const ushort* rowC = C + (size_t)prow * NROWS;

    if (lane == 0) { s_cnt[wv] = 0; s_scnt[wv] = 0; }
    __syncthreads();

    // segment maxima (mono keys): lane holds segs 2*lane, 2*lane+1
    u32 pm  = *(const u32*)&M[(size_t)grow * 128 + 2 * lane];
    u32 klo = pm & 0xFFFFu, khi = pm >> 16;

    // T = largest 16-bit value with count(seg_max >= T) >= KSEL
    u32 T = 0;
    #pragma unroll
    for (int b = 15; b >= 0; --b) {
        u32 cand = T | (1u << b);
        int c = __popcll(__ballot(klo >= cand)) + __popcll(__ballot(khi >= cand));
        if (c >= KSEL) T = cand;
    }

    // survivor-segment id list in LDS (replaces serial ctz chain)
    if (klo >= T) { u32 p = atomicAdd(&s_scnt[wv], 1u); s_seg[wv][p] = 2u * lane; }
    if (khi >= T) { u32 p = atomicAdd(&s_scnt[wv], 1u); s_seg[wv][p] = 2u * lane + 1u; }
    u32 nseg = s_scnt[wv];
    int grp = lane >> 3, sub = lane & 7;   // 8 lanes per segment

    // fast path: up to 32 segments as 4 independent uint4 loads (one mem epoch)
    int  sid[4];
    uint4 vv[4];
    #pragma unroll
    for (int t = 0; t < 4; ++t) {
        u32 ix = (u32)(t * 8 + grp);
        sid[t] = (ix < nseg) ? (int)s_seg[wv][ix] : -1;
    }
    #pragma unroll
    for (int t = 0; t < 4; ++t) {
        if (sid[t] >= 0) vv[t] = *(const uint4*)(rowC + sid[t] * 64 + sub * 8);
    }
    #pragma unroll
    for (int t = 0; t < 4; ++t) {
        if (sid[t] < 0) continue;
        u32 wds[4] = { vv[t].x, vv[t].y, vv[t].z, vv[t].w };
        u32 cbase = (u32)(sid[t] * 64 + sub * 8);
        #pragma unroll
        for (int h = 0; h < 4; ++h) {
            u32 w  = wds[h];
            u32 kA = mono16(w & 0xFFFFu);
            u32 kB = mono16(w >> 16);
            if (kA >= T) { u32 p = atomicAdd(&s_cnt[wv], 1u); if (p < NSURV) s_surv[wv][p] = (kA << 16) | (cbase + 2u * h); }
            if (kB >= T) { u32 p = atomicAdd(&s_cnt[wv], 1u); if (p < NSURV) s_surv[wv][p] = (kB << 16) | (cbase + 2u * h + 1u); }
        }
    }
    // rare tail: nseg > 32
    for (u32 base = 32; base < nseg; base += 8) {
        u32 ix = base + (u32)grp;
        if (ix >= nseg) continue;
        int s = (int)s_seg[wv][ix];
        uint4 v = *(const uint4*)(rowC + s * 64 + sub * 8);
        u32 wds[4] = { v.x, v.y, v.z, v.w };
        u32 cbase = (u32)(s * 64 + sub * 8);
        #pragma unroll
        for (int h = 0; h < 4; ++h) {
            u32 w  = wds[h];
            u32 kA = mono16(w & 0xFFFFu);
            u32 kB = mono16(w >> 16);
            if (kA >= T) { u32 p = atomicAdd(&s_cnt[wv], 1u); if (p < NSURV) s_surv[wv][p] = (kA << 16) | (cbase + 2u * h); }
            if (kB >= T) { u32 p = atomicAdd(&s_cnt[wv], 1u); if (p < NSURV) s_surv[wv][p] = (kB << 16) | (cbase + 2u * h + 1u); }
        }
    }

    u32 cnt = min(s_cnt[wv], (u32)NSURV);     // same-wave LDS: ordered
    int mylab = labels[grow];
    float loss = 0.0f;

    if (cnt <= 64u) {
        // fast path: one survivor per lane; V20 bsearch = 16 ballots
        u32 gg  = ((u32)lane < cnt) ? s_surv[wv][lane] : 0u;
        u32 key = gg >> 16;
        u32 V = 0;
        #pragma unroll
        for (int b = 15; b >= 0; --b) {
            u32 cand = V | (1u << b);
            if (__popcll(__ballot(key >= cand)) >= KSEL) V = cand;
        }
        int cgt  = __popcll(__ballot(key > V));
        int ceq  = __popcll(__ballot(gg != 0 && key == V));
        int need = KSEL - cgt;
        bool incl;
        if (ceq == need) {
            incl = (gg != 0) && (key >= V);
        } else {
            // more ties than slots: take `need` largest cols among ties
            u32 col = gg & 0xFFFFu;
            bool tie = (gg != 0) && (key == V);
            u32 Cv = 0;
            #pragma unroll
            for (int b = 15; b >= 0; --b) {
                u32 cand2 = Cv | (1u << b);
                if (__popcll(__ballot(tie && col >= cand2)) >= need) Cv = cand2;
            }
            incl = (key > V) || (tie && col >= Cv);   // cols unique -> exact
        }
        if (incl) {
            u32 col = gg & 0xFFFFu;
            u32 raw = (key & 0x8000u) ? (key ^ 0x8000u) : (key ^ 0xFFFFu);
            float v = __uint_as_float(raw << 16);
            float p = (v + 1.0f) * 0.5f;
            bool tm = (labels[col] == mylab);
            loss -= tm ? fmaxf(logf(p), -100.0f) : fmaxf(log1pf(-p), -100.0f);
        }
    } else {
        // fallback (rare): 8 survivors per lane
        u32 g[8];
        #pragma unroll
        for (int j = 0; j < 8; ++j) {
            u32 idx = (u32)lane + (u32)j * 64u;
            g[j] = (idx < cnt) ? s_surv[wv][idx] : 0u;
        }
        u32 V = 0;
        #pragma unroll
        for (int b = 15; b >= 0; --b) {
            u32 cand = V | (1u << b);
            int c = 0;
            #pragma unroll
            for (int j = 0; j < 8; ++j)
                c += __popcll(__ballot((g[j] >> 16) >= cand));
            if (c >= KSEL) V = cand;
        }
        int cgt = 0, ceq = 0;
        #pragma unroll
        for (int j = 0; j < 8; ++j) {
            cgt += __popcll(__ballot(g[j] != 0 && (g[j] >> 16) > V));
            ceq += __popcll(__ballot(g[j] != 0 && (g[j] >> 16) == V));
        }
        int need = KSEL - cgt;
        bool all_ties = (ceq == need);
        #pragma unroll
        for (int j = 0; j < 8; ++j) {
            u32 key = g[j] >> 16, col = g[j] & 0xFFFFu;
            if (g[j] != 0 && (key > V || (all_ties && key == V))) {
                u32 raw = (key & 0x8000u) ? (key ^ 0x8000u) : (key ^ 0xFFFFu);
                float v = __uint_as_float(raw << 16);
                float p = (v + 1.0f) * 0.5f;
                bool tm = (labels[col] == mylab);
                loss -= tm ? fmaxf(logf(p), -100.0f) : fmaxf(log1pf(-p), -100.0f);
            }
        }
        if (!all_ties) {
            for (int r = 0; r < need; ++r) {
                u32 best = 0;
                #pragma unroll
                for (int j = 0; j < 8; ++j) {
                    u32 c2 = (g[j] != 0 && (g[j] >> 16) == V) ? ((g[j] & 0xFFFFu) + 1u) : 0u;
                    best = max(best, c2);
                }
                #pragma unroll
                for (int off = 32; off; off >>= 1) best = max(best, (u32)__shfl_xor((int)best, off));
                #pragma unroll
                for (int j = 0; j < 8; ++j) {
                    if (g[j] != 0 && (g[j] >> 16) == V && ((g[j] & 0xFFFFu) + 1u) == best) {
                        u32 col = g[j] & 0xFFFFu;
                        u32 raw = (V & 0x8000u) ? (V ^ 0x8000u) : (V ^ 0xFFFFu);
                        float v = __uint_as_float(raw << 16);
                        float p = (v + 1.0f) * 0.5f;
                        bool tm = (labels[col] == mylab);
                        loss -= tm ? fmaxf(logf(p), -100.0f) : fmaxf(log1pf(-p), -100.0f);
                        g[j] = 0;
                    }
                }
            }
        }
    }

    #pragma unroll
    for (int off = 32; off; off >>= 1) loss += __shfl_xor(loss, off);
    if (lane == 0) partials[grow] = loss;
}

__global__ __launch_bounds__(256) void k_final(const float* __restrict__ partials,
                                               float* __restrict__ out) {
    __shared__ float s[4];
    int tid = threadIdx.x, lane = tid & 63, wvi = tid >> 6;
    const float4* p4 = (const float4*)partials;
    float sum = 0.0f;
    #pragma unroll
    for (int i = 0; i < 8; ++i) {
        float4 v = p4[tid + i * 256];
        sum += v.x + v.y + v.z + v.w;
    }
    #pragma unroll
    for (int off = 32; off; off >>= 1) sum += __shfl_xor(sum, off);
    if (lane == 0) s[wvi] = sum;
    __syncthreads();
    if (tid == 0) out[0] = (s[0] + s[1] + s[2] + s[3]) * (1.0f / (float)(NROWS * KSEL));
}

extern "C" void kernel_launch(void* const* d_in, const int* in_sizes, int n_in,
                              void* d_out, int out_size, void* d_ws, size_t ws_size,
                              hipStream_t stream) {
    const float* batch  = (const float*)d_in[0];
    const int*   labels = (const int*)d_in[1];

    ushort* xn = (ushort*)d_ws;
    ushort* C  = xn + (size_t)NROWS * DIM;
    // M (2 MB) and partials (32 KB) live in the batch input buffer (16 MB):
    // batch is fully consumed by k_norm before k_gemm/k_select write them.
    ushort* M        = (ushort*)d_in[0];
    float*  partials = (float*)((char*)d_in[0] + (4u << 20));

    size_t need_full = (size_t)NROWS * DIM * 2 + (size_t)NROWS * NROWS * 2;

    k_norm<<<NROWS / 4, 256, 0, stream>>>(batch, xn);

    if (ws_size >= need_full) {
        // full symmetric path: 2080 lower-triangle blocks, one select pass
        k_gemm<true><<<dim3(64 * 65 / 2), 256, 0, stream>>>(xn, C, M, 0);
        k_select<<<NROWS / 4, 256, 0, stream>>>(C, M, labels, 0, partials);
    } else {
        // fallback: panel path (24 MB of ws)
        for (int p = 0; p < NROWS / PANEL; ++p) {
            k_gemm<false><<<dim3(64, PANEL / 128), 256, 0, stream>>>(xn, C, M, p * PANEL);
            k_select<<<PANEL / 4, 256, 0, stream>>>(C, M, labels, p * PANEL, partials);
        }
    }
    k_final<<<1, 256, 0, stream>>>(partials, (float*)d_out);
}